// Round 1
// baseline (602.424 us; speedup 1.0000x reference)
//
#include <hip/hip_runtime.h>

#define NEG_SLOPE 0.2f

__device__ __forceinline__ float lrelu(float x) {
    return fmaxf(x, 0.0f) + NEG_SLOPE * fminf(x, 0.0f);
}

// ---------------- CSR construction ----------------

__global__ void hist_kernel(const int* __restrict__ dst, int* __restrict__ cnt, int E) {
    int e = blockIdx.x * 256 + threadIdx.x;
    if (e < E) atomicAdd(&cnt[dst[e]], 1);
}

__global__ __launch_bounds__(1024) void scan_kernel(const int* __restrict__ cnt,
                                                    int* __restrict__ rp, int n) {
    __shared__ int sums[1024];
    int tid = threadIdx.x;
    int CH = (n + 1023) >> 10;
    int base = tid * CH;
    int local = 0;
    for (int i = 0; i < CH; ++i) {
        int idx = base + i;
        if (idx < n) local += cnt[idx];
    }
    sums[tid] = local;
    __syncthreads();
    for (int off = 1; off < 1024; off <<= 1) {
        int v = (tid >= off) ? sums[tid - off] : 0;
        __syncthreads();
        sums[tid] += v;
        __syncthreads();
    }
    int run = (tid == 0) ? 0 : sums[tid - 1];
    for (int i = 0; i < CH; ++i) {
        int idx = base + i;
        if (idx < n) { rp[idx] = run; run += cnt[idx]; }
    }
    if (tid == 1023) rp[n] = sums[1023];
}

__global__ void scatter_kernel(const int* __restrict__ src, const int* __restrict__ dst,
                               const int* __restrict__ rp, int* __restrict__ fill,
                               int* __restrict__ csr, int E) {
    int e = blockIdx.x * 256 + threadIdx.x;
    if (e < E) {
        int d = dst[e];
        int pos = rp[d] + atomicAdd(&fill[d], 1);
        csr[pos] = src[e];
    }
}

// ---------------- GEMM: C[M,NC] = A[M,128] @ B[128,NC] ----------------
// BM=128, BN=NC(<=128), BK=32; 256 threads; 8x8 micro-tile.

template <int NC>
__global__ __launch_bounds__(256) void gemm_k128(const float* __restrict__ A,
                                                 const float* __restrict__ B,
                                                 float* __restrict__ C, int M) {
    constexpr int BSTR = (NC + 3) & ~3;  // 128 or 124 (16B-aligned rows)
    __shared__ float As[128][36];
    __shared__ float Bs[32][BSTR];

    float acc[8][8];
#pragma unroll
    for (int i = 0; i < 8; ++i)
#pragma unroll
        for (int j = 0; j < 8; ++j) acc[i][j] = 0.0f;

    const int trow = threadIdx.x >> 4;  // 0..15
    const int tcol = threadIdx.x & 15;  // 0..15
    const int rbase = blockIdx.x * 128;

    for (int kt = 0; kt < 4; ++kt) {
        // stage A tile [128][32]
#pragma unroll
        for (int q = 0; q < 4; ++q) {
            int v = threadIdx.x + q * 256;
            int r = v >> 3, k4 = v & 7;
            float4 val = make_float4(0.f, 0.f, 0.f, 0.f);
            int row = rbase + r;
            if (row < M) val = *(const float4*)&A[row * 128 + kt * 32 + k4 * 4];
            *(float4*)&As[r][k4 * 4] = val;
        }
        // stage B tile [32][NC] (pad cols with 0)
        for (int i = threadIdx.x; i < 32 * BSTR; i += 256) {
            int k = i / BSTR, c = i % BSTR;
            Bs[k][c] = (c < NC) ? B[(kt * 32 + k) * NC + c] : 0.0f;
        }
        __syncthreads();

#pragma unroll
        for (int k = 0; k < 32; k += 4) {
            float a_[8][4];
#pragma unroll
            for (int i = 0; i < 8; ++i) {
                float4 t = *(const float4*)&As[trow * 8 + i][k];
                a_[i][0] = t.x; a_[i][1] = t.y; a_[i][2] = t.z; a_[i][3] = t.w;
            }
#pragma unroll
            for (int kk = 0; kk < 4; ++kk) {
                float4 bx = *(const float4*)&Bs[k + kk][tcol * 8];
                float4 by = *(const float4*)&Bs[k + kk][tcol * 8 + 4];
#pragma unroll
                for (int i = 0; i < 8; ++i) {
                    float a = a_[i][kk];
                    acc[i][0] = fmaf(a, bx.x, acc[i][0]);
                    acc[i][1] = fmaf(a, bx.y, acc[i][1]);
                    acc[i][2] = fmaf(a, bx.z, acc[i][2]);
                    acc[i][3] = fmaf(a, bx.w, acc[i][3]);
                    acc[i][4] = fmaf(a, by.x, acc[i][4]);
                    acc[i][5] = fmaf(a, by.y, acc[i][5]);
                    acc[i][6] = fmaf(a, by.z, acc[i][6]);
                    acc[i][7] = fmaf(a, by.w, acc[i][7]);
                }
            }
        }
        __syncthreads();
    }

#pragma unroll
    for (int i = 0; i < 8; ++i) {
        int row = rbase + trow * 8 + i;
        if (row >= M) continue;
        if constexpr (NC == 128) {
            float4 v0 = make_float4(acc[i][0], acc[i][1], acc[i][2], acc[i][3]);
            float4 v1 = make_float4(acc[i][4], acc[i][5], acc[i][6], acc[i][7]);
            *(float4*)&C[row * 128 + tcol * 8] = v0;
            *(float4*)&C[row * 128 + tcol * 8 + 4] = v1;
        } else {
#pragma unroll
            for (int j = 0; j < 8; ++j) {
                int c = tcol * 8 + j;
                if (c < NC) C[row * NC + c] = acc[i][j];
            }
        }
    }
}

// ---------------- attention logit dot products ----------------

// layer 1: 8 heads x 16 dims; one thread per (row, head)
__global__ void al1_kernel(const float* __restrict__ h1, const float* __restrict__ as,
                           const float* __restrict__ ad, float* __restrict__ alS,
                           float* __restrict__ alD, int N) {
    int g = blockIdx.x * 256 + threadIdx.x;
    if (g >= N * 8) return;
    int r = g >> 3, h = g & 7;
    const float* hp = h1 + r * 128 + h * 16;
    const float* sp = as + h * 16;
    const float* dp = ad + h * 16;
    float s = 0.f, d = 0.f;
#pragma unroll
    for (int q = 0; q < 16; ++q) {
        float v = hp[q];
        s = fmaf(v, sp[q], s);
        d = fmaf(v, dp[q], d);
    }
    alS[g] = s;
    alD[g] = d;
}

// layer 2: 1 head x NC dims; one wave per row
__global__ __launch_bounds__(256) void al2_kernel(const float* __restrict__ h3,
                                                  const float* __restrict__ as,
                                                  const float* __restrict__ ad,
                                                  float* __restrict__ alS,
                                                  float* __restrict__ alD, int N, int NC) {
    int lane = threadIdx.x & 63;
    int r = blockIdx.x * 4 + (threadIdx.x >> 6);
    if (r >= N) return;
    float s = 0.f, d = 0.f;
    for (int c = lane; c < NC; c += 64) {
        float v = h3[r * NC + c];
        s = fmaf(v, as[c], s);
        d = fmaf(v, ad[c], d);
    }
#pragma unroll
    for (int off = 32; off; off >>= 1) {
        s += __shfl_down(s, off);
        d += __shfl_down(d, off);
    }
    if (lane == 0) { alS[r] = s; alD[r] = d; }
}

// ---------------- layer-1 aggregation (8 heads x 16 dims) ----------------
// one block (128 threads) per dst node; thread = (head, dim)
__global__ __launch_bounds__(128) void agg1_kernel(
    const float* __restrict__ h1, const float* __restrict__ alS,
    const float* __restrict__ alD, const float* __restrict__ b1,
    const int* __restrict__ rp, const int* __restrict__ csr,
    float* __restrict__ h2, int N) {
    int t = blockIdx.x;
    int tid = threadIdx.x;
    int h = tid >> 4;
    float adT = alD[t * 8 + h];
    int e0 = rp[t], e1 = rp[t + 1];

    float lself = lrelu(alS[t * 8 + h] + adT);
    float m = lself;
    for (int e = e0; e < e1; ++e) {
        int s = csr[e];
        m = fmaxf(m, lrelu(alS[s * 8 + h] + adT));
    }

    float ex = __expf(lself - m);
    float dsum = ex;
    float facc = ex * h1[t * 128 + tid];
    for (int e = e0; e < e1; ++e) {
        int s = csr[e];
        float w = __expf(lrelu(alS[s * 8 + h] + adT) - m);
        dsum += w;
        facc = fmaf(w, h1[s * 128 + tid], facc);
    }
    float o = facc / dsum + b1[tid];
    h2[t * 128 + tid] = fmaxf(o, 0.0f);
}

// ---------------- layer-2 aggregation (1 head x NC dims) ----------------
__global__ __launch_bounds__(128) void agg2_kernel(
    const float* __restrict__ h3, const float* __restrict__ alS,
    const float* __restrict__ alD, const float* __restrict__ b2,
    const int* __restrict__ rp, const int* __restrict__ csr,
    float* __restrict__ out, int N, int NC) {
    int t = blockIdx.x;
    int tid = threadIdx.x;
    float adT = alD[t];
    int e0 = rp[t], e1 = rp[t + 1];

    float lself = lrelu(alS[t] + adT);
    float m = lself;
    for (int e = e0; e < e1; ++e) {
        int s = csr[e];
        m = fmaxf(m, lrelu(alS[s] + adT));
    }

    float ex = __expf(lself - m);
    float dsum = ex;
    float facc = (tid < NC) ? ex * h3[t * NC + tid] : 0.0f;
    for (int e = e0; e < e1; ++e) {
        int s = csr[e];
        float w = __expf(lrelu(alS[s] + adT) - m);
        dsum += w;
        if (tid < NC) facc = fmaf(w, h3[s * NC + tid], facc);
    }
    if (tid < NC) out[t * NC + tid] = facc / dsum + b2[tid];
}

// ---------------- host launcher ----------------

extern "C" void kernel_launch(void* const* d_in, const int* in_sizes, int n_in,
                              void* d_out, int out_size, void* d_ws, size_t ws_size,
                              hipStream_t stream) {
    const float* x   = (const float*)d_in[0];
    const int*   ei  = (const int*)d_in[1];
    const float* W1  = (const float*)d_in[2];
    const float* aS1 = (const float*)d_in[3];
    const float* aD1 = (const float*)d_in[4];
    const float* b1  = (const float*)d_in[5];
    const float* W2  = (const float*)d_in[6];
    const float* aS2 = (const float*)d_in[7];
    const float* aD2 = (const float*)d_in[8];
    const float* b2  = (const float*)d_in[9];
    float* out = (float*)d_out;

    const int N = in_sizes[0] / 128;   // 50000
    const int E = in_sizes[1] / 2;     // 800000
    const int NC2 = 121;

    // workspace layout (256B aligned)
    size_t off = 0;
    auto alloc = [&](size_t bytes) {
        size_t o = off;
        off = (off + bytes + 255) & ~(size_t)255;
        return o;
    };
    char* ws = (char*)d_ws;
    int*   cnt   = (int*)(ws + alloc((size_t)N * 4));
    int*   fill  = (int*)(ws + alloc((size_t)N * 4));
    int*   rp    = (int*)(ws + alloc((size_t)(N + 1) * 4));
    int*   csr   = (int*)(ws + alloc((size_t)E * 4));
    float* alS1  = (float*)(ws + alloc((size_t)N * 8 * 4));
    float* alD1  = (float*)(ws + alloc((size_t)N * 8 * 4));
    float* alS2  = (float*)(ws + alloc((size_t)N * 4));
    float* alD2  = (float*)(ws + alloc((size_t)N * 4));
    float* h1    = (float*)(ws + alloc((size_t)N * 128 * 4));
    float* h2    = (float*)(ws + alloc((size_t)N * 128 * 4));
    float* h3    = h1;  // h1 dead after agg1; reuse for h3 [N,121]
    if (ws_size < off) return;  // insufficient workspace -> fail loudly

    const int* src = ei;
    const int* dst = ei + E;

    hipMemsetAsync(cnt, 0, (size_t)N * 4, stream);
    hipMemsetAsync(fill, 0, (size_t)N * 4, stream);

    int eb = (E + 255) / 256;
    hist_kernel<<<eb, 256, 0, stream>>>(dst, cnt, E);
    scan_kernel<<<1, 1024, 0, stream>>>(cnt, rp, N);
    scatter_kernel<<<eb, 256, 0, stream>>>(src, dst, rp, fill, csr, E);

    int gb = (N + 127) / 128;
    gemm_k128<128><<<gb, 256, 0, stream>>>(x, W1, h1, N);
    al1_kernel<<<(N * 8 + 255) / 256, 256, 0, stream>>>(h1, aS1, aD1, alS1, alD1, N);
    agg1_kernel<<<N, 128, 0, stream>>>(h1, alS1, alD1, b1, rp, csr, h2, N);

    gemm_k128<121><<<gb, 256, 0, stream>>>(h2, W2, h3, N);
    al2_kernel<<<(N + 3) / 4, 256, 0, stream>>>(h3, aS2, aD2, alS2, alD2, N, NC2);
    agg2_kernel<<<N, 128, 0, stream>>>(h3, alS2, alD2, b2, rp, csr, out, N, NC2);
}

// Round 2
// 464.081 us; speedup vs baseline: 1.2981x; 1.2981x over previous
//
#include <hip/hip_runtime.h>

#define NEG_SLOPE 0.2f

__device__ __forceinline__ float lrelu(float x) {
    return fmaxf(x, 0.0f) + NEG_SLOPE * fminf(x, 0.0f);
}

// monotonic float<->uint key for atomicMax on floats (any sign)
__device__ __forceinline__ unsigned fkey(float f) {
    unsigned u = __float_as_uint(f);
    return (u & 0x80000000u) ? ~u : (u | 0x80000000u);
}
__device__ __forceinline__ float funkey(unsigned k) {
    return __uint_as_float((k & 0x80000000u) ? (k & 0x7fffffffu) : ~k);
}

// ---------------- CSR construction ----------------

__global__ void hist_kernel(const int* __restrict__ dst, int* __restrict__ cnt, int E) {
    int e = blockIdx.x * 256 + threadIdx.x;
    if (e < E) atomicAdd(&cnt[dst[e]], 1);
}

__global__ __launch_bounds__(1024) void scan_kernel(const int* __restrict__ cnt,
                                                    int* __restrict__ rp, int n) {
    __shared__ int sums[1024];
    int tid = threadIdx.x;
    int CH = (n + 1023) >> 10;
    int base = tid * CH;
    int local = 0;
    for (int i = 0; i < CH; ++i) {
        int idx = base + i;
        if (idx < n) local += cnt[idx];
    }
    sums[tid] = local;
    __syncthreads();
    for (int off = 1; off < 1024; off <<= 1) {
        int v = (tid >= off) ? sums[tid - off] : 0;
        __syncthreads();
        sums[tid] += v;
        __syncthreads();
    }
    int run = (tid == 0) ? 0 : sums[tid - 1];
    for (int i = 0; i < CH; ++i) {
        int idx = base + i;
        if (idx < n) { rp[idx] = run; run += cnt[idx]; }
    }
    if (tid == 1023) rp[n] = sums[1023];
}

__global__ void scatter_kernel(const int* __restrict__ src, const int* __restrict__ dst,
                               const int* __restrict__ rp, int* __restrict__ fill,
                               int* __restrict__ csr, int E) {
    int e = blockIdx.x * 256 + threadIdx.x;
    if (e < E) {
        int d = dst[e];
        int pos = rp[d] + atomicAdd(&fill[d], 1);
        csr[pos] = src[e];
    }
}

// ---------------- global per-head max of alS (for softmax stability) ----------------
// H divides 256 and all reduction offsets (8..128) so each smem slot keeps its head.

template <int H>
__global__ __launch_bounds__(256) void gmax_kernel(const float* __restrict__ a,
                                                   unsigned* __restrict__ gm, int total) {
    __shared__ unsigned sm[256];
    unsigned loc = 0;
    int stride = 256 * gridDim.x;  // multiple of H (H is 1 or 8)
    for (int i = blockIdx.x * 256 + threadIdx.x; i < total; i += stride)
        loc = max(loc, fkey(a[i]));
    sm[threadIdx.x] = loc;
    __syncthreads();
    for (int off = 128; off >= H; off >>= 1) {
        if (threadIdx.x < off) sm[threadIdx.x] = max(sm[threadIdx.x], sm[threadIdx.x + off]);
        __syncthreads();
    }
    if (threadIdx.x < H) atomicMax(&gm[threadIdx.x], sm[threadIdx.x]);
}

// ---------------- GEMM: C[M,NC] = A[M,128] @ B[128,NC] ----------------

template <int NC>
__global__ __launch_bounds__(256) void gemm_k128(const float* __restrict__ A,
                                                 const float* __restrict__ B,
                                                 float* __restrict__ C, int M) {
    constexpr int BSTR = (NC + 3) & ~3;
    __shared__ float As[128][36];
    __shared__ float Bs[32][BSTR];

    float acc[8][8];
#pragma unroll
    for (int i = 0; i < 8; ++i)
#pragma unroll
        for (int j = 0; j < 8; ++j) acc[i][j] = 0.0f;

    const int trow = threadIdx.x >> 4;
    const int tcol = threadIdx.x & 15;
    const int rbase = blockIdx.x * 128;

    for (int kt = 0; kt < 4; ++kt) {
#pragma unroll
        for (int q = 0; q < 4; ++q) {
            int v = threadIdx.x + q * 256;
            int r = v >> 3, k4 = v & 7;
            float4 val = make_float4(0.f, 0.f, 0.f, 0.f);
            int row = rbase + r;
            if (row < M) val = *(const float4*)&A[row * 128 + kt * 32 + k4 * 4];
            *(float4*)&As[r][k4 * 4] = val;
        }
        for (int i = threadIdx.x; i < 32 * BSTR; i += 256) {
            int k = i / BSTR, c = i % BSTR;
            Bs[k][c] = (c < NC) ? B[(kt * 32 + k) * NC + c] : 0.0f;
        }
        __syncthreads();

#pragma unroll
        for (int k = 0; k < 32; k += 4) {
            float a_[8][4];
#pragma unroll
            for (int i = 0; i < 8; ++i) {
                float4 t = *(const float4*)&As[trow * 8 + i][k];
                a_[i][0] = t.x; a_[i][1] = t.y; a_[i][2] = t.z; a_[i][3] = t.w;
            }
#pragma unroll
            for (int kk = 0; kk < 4; ++kk) {
                float4 bx = *(const float4*)&Bs[k + kk][tcol * 8];
                float4 by = *(const float4*)&Bs[k + kk][tcol * 8 + 4];
#pragma unroll
                for (int i = 0; i < 8; ++i) {
                    float a = a_[i][kk];
                    acc[i][0] = fmaf(a, bx.x, acc[i][0]);
                    acc[i][1] = fmaf(a, bx.y, acc[i][1]);
                    acc[i][2] = fmaf(a, bx.z, acc[i][2]);
                    acc[i][3] = fmaf(a, bx.w, acc[i][3]);
                    acc[i][4] = fmaf(a, by.x, acc[i][4]);
                    acc[i][5] = fmaf(a, by.y, acc[i][5]);
                    acc[i][6] = fmaf(a, by.z, acc[i][6]);
                    acc[i][7] = fmaf(a, by.w, acc[i][7]);
                }
            }
        }
        __syncthreads();
    }

#pragma unroll
    for (int i = 0; i < 8; ++i) {
        int row = rbase + trow * 8 + i;
        if (row >= M) continue;
        if constexpr (NC == 128) {
            float4 v0 = make_float4(acc[i][0], acc[i][1], acc[i][2], acc[i][3]);
            float4 v1 = make_float4(acc[i][4], acc[i][5], acc[i][6], acc[i][7]);
            *(float4*)&C[row * 128 + tcol * 8] = v0;
            *(float4*)&C[row * 128 + tcol * 8 + 4] = v1;
        } else {
#pragma unroll
            for (int j = 0; j < 8; ++j) {
                int c = tcol * 8 + j;
                if (c < NC) C[row * NC + c] = acc[i][j];
            }
        }
    }
}

// ---------------- attention logit dot products ----------------

__global__ void al1_kernel(const float* __restrict__ h1, const float* __restrict__ as,
                           const float* __restrict__ ad, float* __restrict__ alS,
                           float* __restrict__ alD, int N) {
    int g = blockIdx.x * 256 + threadIdx.x;
    if (g >= N * 8) return;
    int r = g >> 3, h = g & 7;
    const float* hp = h1 + r * 128 + h * 16;
    const float* sp = as + h * 16;
    const float* dp = ad + h * 16;
    float s = 0.f, d = 0.f;
#pragma unroll
    for (int q = 0; q < 16; ++q) {
        float v = hp[q];
        s = fmaf(v, sp[q], s);
        d = fmaf(v, dp[q], d);
    }
    alS[g] = s;
    alD[g] = d;
}

__global__ __launch_bounds__(256) void al2_kernel(const float* __restrict__ h3,
                                                  const float* __restrict__ as,
                                                  const float* __restrict__ ad,
                                                  float* __restrict__ alS,
                                                  float* __restrict__ alD, int N, int NC) {
    int lane = threadIdx.x & 63;
    int r = blockIdx.x * 4 + (threadIdx.x >> 6);
    if (r >= N) return;
    float s = 0.f, d = 0.f;
    for (int c = lane; c < NC; c += 64) {
        float v = h3[r * NC + c];
        s = fmaf(v, as[c], s);
        d = fmaf(v, ad[c], d);
    }
#pragma unroll
    for (int off = 32; off; off >>= 1) {
        s += __shfl_down(s, off);
        d += __shfl_down(d, off);
    }
    if (lane == 0) { alS[r] = s; alD[r] = d; }
}

// ---------------- layer-1 aggregation: single pass, global-max stabilized ----------------

__global__ __launch_bounds__(128) void agg1_kernel(
    const float* __restrict__ h1, const float* __restrict__ alS,
    const float* __restrict__ alD, const float* __restrict__ b1,
    const int* __restrict__ rp, const int* __restrict__ csr,
    const unsigned* __restrict__ gm, float* __restrict__ h2, int N) {
    int t = blockIdx.x;
    int tid = threadIdx.x;
    int h = tid >> 4;
    float adT = alD[t * 8 + h];
    float m = lrelu(funkey(gm[h]) + adT);  // upper bound of all logits into t (this head)
    int e0 = rp[t], e1 = rp[t + 1];

    float ex = __expf(lrelu(alS[t * 8 + h] + adT) - m);  // self loop
    float dsum = ex;
    float facc = ex * h1[t * 128 + tid];

    int e = e0;
    for (; e + 2 <= e1; e += 2) {
        int s0 = csr[e], s1 = csr[e + 1];
        float w0 = __expf(lrelu(alS[s0 * 8 + h] + adT) - m);
        float w1 = __expf(lrelu(alS[s1 * 8 + h] + adT) - m);
        float f0 = h1[s0 * 128 + tid];
        float f1 = h1[s1 * 128 + tid];
        dsum += w0 + w1;
        facc = fmaf(w0, f0, facc);
        facc = fmaf(w1, f1, facc);
    }
    if (e < e1) {
        int s0 = csr[e];
        float w0 = __expf(lrelu(alS[s0 * 8 + h] + adT) - m);
        dsum += w0;
        facc = fmaf(w0, h1[s0 * 128 + tid], facc);
    }
    float o = facc / dsum + b1[tid];
    h2[t * 128 + tid] = fmaxf(o, 0.0f);
}

// ---------------- layer-2 aggregation: single pass ----------------

__global__ __launch_bounds__(128) void agg2_kernel(
    const float* __restrict__ h3, const float* __restrict__ alS,
    const float* __restrict__ alD, const float* __restrict__ b2,
    const int* __restrict__ rp, const int* __restrict__ csr,
    const unsigned* __restrict__ gm, float* __restrict__ out, int N, int NC) {
    int t = blockIdx.x;
    int tid = threadIdx.x;
    float adT = alD[t];
    float m = lrelu(funkey(gm[0]) + adT);
    int e0 = rp[t], e1 = rp[t + 1];

    float ex = __expf(lrelu(alS[t] + adT) - m);
    float dsum = ex;
    float facc = (tid < NC) ? ex * h3[t * NC + tid] : 0.0f;

    int e = e0;
    for (; e + 2 <= e1; e += 2) {
        int s0 = csr[e], s1 = csr[e + 1];
        float w0 = __expf(lrelu(alS[s0] + adT) - m);
        float w1 = __expf(lrelu(alS[s1] + adT) - m);
        float f0 = (tid < NC) ? h3[s0 * NC + tid] : 0.0f;
        float f1 = (tid < NC) ? h3[s1 * NC + tid] : 0.0f;
        dsum += w0 + w1;
        facc = fmaf(w0, f0, facc);
        facc = fmaf(w1, f1, facc);
    }
    if (e < e1) {
        int s0 = csr[e];
        float w0 = __expf(lrelu(alS[s0] + adT) - m);
        dsum += w0;
        if (tid < NC) facc = fmaf(w0, h3[s0 * NC + tid], facc);
    }
    if (tid < NC) out[t * NC + tid] = facc / dsum + b2[tid];
}

// ---------------- host launcher ----------------

extern "C" void kernel_launch(void* const* d_in, const int* in_sizes, int n_in,
                              void* d_out, int out_size, void* d_ws, size_t ws_size,
                              hipStream_t stream) {
    const float* x   = (const float*)d_in[0];
    const int*   ei  = (const int*)d_in[1];
    const float* W1  = (const float*)d_in[2];
    const float* aS1 = (const float*)d_in[3];
    const float* aD1 = (const float*)d_in[4];
    const float* b1  = (const float*)d_in[5];
    const float* W2  = (const float*)d_in[6];
    const float* aS2 = (const float*)d_in[7];
    const float* aD2 = (const float*)d_in[8];
    const float* b2  = (const float*)d_in[9];
    float* out = (float*)d_out;

    const int N = in_sizes[0] / 128;   // 50000
    const int E = in_sizes[1] / 2;     // 800000
    const int NC2 = 121;

    size_t off = 0;
    auto alloc = [&](size_t bytes) {
        size_t o = off;
        off = (off + bytes + 255) & ~(size_t)255;
        return o;
    };
    char* ws = (char*)d_ws;
    int*      cnt  = (int*)(ws + alloc((size_t)N * 4));
    int*      fill = (int*)(ws + alloc((size_t)N * 4));
    int*      rp   = (int*)(ws + alloc((size_t)(N + 1) * 4));
    int*      csr  = (int*)(ws + alloc((size_t)E * 4));
    float*    alS1 = (float*)(ws + alloc((size_t)N * 8 * 4));
    float*    alD1 = (float*)(ws + alloc((size_t)N * 8 * 4));
    float*    alS2 = (float*)(ws + alloc((size_t)N * 4));
    float*    alD2 = (float*)(ws + alloc((size_t)N * 4));
    unsigned* gm1  = (unsigned*)(ws + alloc(8 * 4));
    unsigned* gm2  = (unsigned*)(ws + alloc(4));
    float*    h1   = (float*)(ws + alloc((size_t)N * 128 * 4));
    float*    h2   = (float*)(ws + alloc((size_t)N * 128 * 4));
    float*    h3   = h1;  // h1 dead after agg1
    if (ws_size < off) return;

    const int* src = ei;
    const int* dst = ei + E;

    hipMemsetAsync(cnt, 0, (size_t)N * 4, stream);
    hipMemsetAsync(fill, 0, (size_t)N * 4, stream);
    hipMemsetAsync(gm1, 0, 8 * 4, stream);
    hipMemsetAsync(gm2, 0, 4, stream);

    int eb = (E + 255) / 256;
    hist_kernel<<<eb, 256, 0, stream>>>(dst, cnt, E);
    scan_kernel<<<1, 1024, 0, stream>>>(cnt, rp, N);
    scatter_kernel<<<eb, 256, 0, stream>>>(src, dst, rp, fill, csr, E);

    int gb = (N + 127) / 128;
    gemm_k128<128><<<gb, 256, 0, stream>>>(x, W1, h1, N);
    al1_kernel<<<(N * 8 + 255) / 256, 256, 0, stream>>>(h1, aS1, aD1, alS1, alD1, N);
    gmax_kernel<8><<<128, 256, 0, stream>>>(alS1, gm1, N * 8);
    agg1_kernel<<<N, 128, 0, stream>>>(h1, alS1, alD1, b1, rp, csr, gm1, h2, N);

    gemm_k128<121><<<gb, 256, 0, stream>>>(h2, W2, h3, N);
    al2_kernel<<<(N + 3) / 4, 256, 0, stream>>>(h3, aS2, aD2, alS2, alD2, N, NC2);
    gmax_kernel<1><<<128, 256, 0, stream>>>(alS2, gm2, N);
    agg2_kernel<<<N, 128, 0, stream>>>(h3, alS2, alD2, b2, rp, csr, gm2, out, N, NC2);
}

// Round 3
// 380.424 us; speedup vs baseline: 1.5836x; 1.2199x over previous
//
#include <hip/hip_runtime.h>

#define NEG_SLOPE 0.2f

__device__ __forceinline__ float lrelu(float x) {
    return fmaxf(x, 0.0f) + NEG_SLOPE * fminf(x, 0.0f);
}

// monotonic float<->uint key for atomicMax on floats (any sign)
__device__ __forceinline__ unsigned fkey(float f) {
    unsigned u = __float_as_uint(f);
    return (u & 0x80000000u) ? ~u : (u | 0x80000000u);
}
__device__ __forceinline__ float funkey(unsigned k) {
    return __uint_as_float((k & 0x80000000u) ? (k & 0x7fffffffu) : ~k);
}

// ---------------- CSR construction ----------------

__global__ void hist_kernel(const int* __restrict__ dst, int* __restrict__ cnt, int E) {
    int e = blockIdx.x * 256 + threadIdx.x;
    if (e < E) atomicAdd(&cnt[dst[e]], 1);
}

// ---- 3-phase exclusive scan of cnt[0..n) -> rp[0..n]  (1024 elems / block) ----

__global__ __launch_bounds__(256) void scan_reduce(const int* __restrict__ cnt,
                                                   int* __restrict__ bsum, int n) {
    __shared__ int sm[256];
    int base = blockIdx.x * 1024 + threadIdx.x * 4;
    int s = 0;
#pragma unroll
    for (int j = 0; j < 4; ++j) {
        int i = base + j;
        if (i < n) s += cnt[i];
    }
    sm[threadIdx.x] = s;
    __syncthreads();
#pragma unroll
    for (int off = 128; off >= 1; off >>= 1) {
        if (threadIdx.x < off) sm[threadIdx.x] += sm[threadIdx.x + off];
        __syncthreads();
    }
    if (threadIdx.x == 0) bsum[blockIdx.x] = sm[0];
}

// nb <= 64 (one wave). Converts bsum to its exclusive scan.
__global__ __launch_bounds__(64) void scan_bsum(int* __restrict__ bsum, int nb) {
    int v = (threadIdx.x < (unsigned)nb) ? bsum[threadIdx.x] : 0;
    int x = v;
#pragma unroll
    for (int off = 1; off < 64; off <<= 1) {
        int y = __shfl_up(x, off);
        if ((int)threadIdx.x >= off) x += y;
    }
    if (threadIdx.x < (unsigned)nb) bsum[threadIdx.x] = x - v;  // exclusive
}

__global__ __launch_bounds__(256) void scan_write(const int* __restrict__ cnt,
                                                  const int* __restrict__ bsum,
                                                  int* __restrict__ rp, int n) {
    __shared__ int sm[256];
    int base = blockIdx.x * 1024 + threadIdx.x * 4;
    int v[4];
    int s = 0;
#pragma unroll
    for (int j = 0; j < 4; ++j) {
        int i = base + j;
        v[j] = (i < n) ? cnt[i] : 0;
        s += v[j];
    }
    sm[threadIdx.x] = s;
    __syncthreads();
#pragma unroll
    for (int off = 1; off < 256; off <<= 1) {
        int y = (threadIdx.x >= off) ? sm[threadIdx.x - off] : 0;
        __syncthreads();
        sm[threadIdx.x] += y;
        __syncthreads();
    }
    int run = sm[threadIdx.x] - s + bsum[blockIdx.x];  // exclusive prefix for this thread
#pragma unroll
    for (int j = 0; j < 4; ++j) {
        int i = base + j;
        if (i < n) {
            rp[i] = run;
            run += v[j];
            if (i == n - 1) rp[n] = run;
        }
    }
}

__global__ void scatter_kernel(const int* __restrict__ src, const int* __restrict__ dst,
                               const int* __restrict__ rp, int* __restrict__ fill,
                               int* __restrict__ csr, int E) {
    int e = blockIdx.x * 256 + threadIdx.x;
    if (e < E) {
        int d = dst[e];
        int pos = rp[d] + atomicAdd(&fill[d], 1);
        csr[pos] = src[e];
    }
}

// ---------------- global per-head max of alS (for softmax stability) ----------------

template <int H>
__global__ __launch_bounds__(256) void gmax_kernel(const float* __restrict__ a,
                                                   unsigned* __restrict__ gm, int total) {
    __shared__ unsigned sm[256];
    unsigned loc = 0;
    int stride = 256 * gridDim.x;
    for (int i = blockIdx.x * 256 + threadIdx.x; i < total; i += stride)
        loc = max(loc, fkey(a[i]));
    sm[threadIdx.x] = loc;
    __syncthreads();
    for (int off = 128; off >= H; off >>= 1) {
        if (threadIdx.x < off) sm[threadIdx.x] = max(sm[threadIdx.x], sm[threadIdx.x + off]);
        __syncthreads();
    }
    if (threadIdx.x < H) atomicMax(&gm[threadIdx.x], sm[threadIdx.x]);
}

// ---------------- GEMM: C[M,NC] = A[M,128] @ B[128,NC] ----------------

template <int NC>
__global__ __launch_bounds__(256) void gemm_k128(const float* __restrict__ A,
                                                 const float* __restrict__ B,
                                                 float* __restrict__ C, int M) {
    constexpr int BSTR = (NC + 3) & ~3;
    __shared__ float As[128][36];
    __shared__ float Bs[32][BSTR];

    float acc[8][8];
#pragma unroll
    for (int i = 0; i < 8; ++i)
#pragma unroll
        for (int j = 0; j < 8; ++j) acc[i][j] = 0.0f;

    const int trow = threadIdx.x >> 4;
    const int tcol = threadIdx.x & 15;
    const int rbase = blockIdx.x * 128;

    for (int kt = 0; kt < 4; ++kt) {
#pragma unroll
        for (int q = 0; q < 4; ++q) {
            int v = threadIdx.x + q * 256;
            int r = v >> 3, k4 = v & 7;
            float4 val = make_float4(0.f, 0.f, 0.f, 0.f);
            int row = rbase + r;
            if (row < M) val = *(const float4*)&A[row * 128 + kt * 32 + k4 * 4];
            *(float4*)&As[r][k4 * 4] = val;
        }
        for (int i = threadIdx.x; i < 32 * BSTR; i += 256) {
            int k = i / BSTR, c = i % BSTR;
            Bs[k][c] = (c < NC) ? B[(kt * 32 + k) * NC + c] : 0.0f;
        }
        __syncthreads();

#pragma unroll
        for (int k = 0; k < 32; k += 4) {
            float a_[8][4];
#pragma unroll
            for (int i = 0; i < 8; ++i) {
                float4 t = *(const float4*)&As[trow * 8 + i][k];
                a_[i][0] = t.x; a_[i][1] = t.y; a_[i][2] = t.z; a_[i][3] = t.w;
            }
#pragma unroll
            for (int kk = 0; kk < 4; ++kk) {
                float4 bx = *(const float4*)&Bs[k + kk][tcol * 8];
                float4 by = *(const float4*)&Bs[k + kk][tcol * 8 + 4];
#pragma unroll
                for (int i = 0; i < 8; ++i) {
                    float a = a_[i][kk];
                    acc[i][0] = fmaf(a, bx.x, acc[i][0]);
                    acc[i][1] = fmaf(a, bx.y, acc[i][1]);
                    acc[i][2] = fmaf(a, bx.z, acc[i][2]);
                    acc[i][3] = fmaf(a, bx.w, acc[i][3]);
                    acc[i][4] = fmaf(a, by.x, acc[i][4]);
                    acc[i][5] = fmaf(a, by.y, acc[i][5]);
                    acc[i][6] = fmaf(a, by.z, acc[i][6]);
                    acc[i][7] = fmaf(a, by.w, acc[i][7]);
                }
            }
        }
        __syncthreads();
    }

#pragma unroll
    for (int i = 0; i < 8; ++i) {
        int row = rbase + trow * 8 + i;
        if (row >= M) continue;
        if constexpr (NC == 128) {
            float4 v0 = make_float4(acc[i][0], acc[i][1], acc[i][2], acc[i][3]);
            float4 v1 = make_float4(acc[i][4], acc[i][5], acc[i][6], acc[i][7]);
            *(float4*)&C[row * 128 + tcol * 8] = v0;
            *(float4*)&C[row * 128 + tcol * 8 + 4] = v1;
        } else {
#pragma unroll
            for (int j = 0; j < 8; ++j) {
                int c = tcol * 8 + j;
                if (c < NC) C[row * NC + c] = acc[i][j];
            }
        }
    }
}

// ---------------- attention logit dot products ----------------

__global__ void al1_kernel(const float* __restrict__ h1, const float* __restrict__ as,
                           const float* __restrict__ ad, float* __restrict__ alS,
                           float* __restrict__ alD, int N) {
    int g = blockIdx.x * 256 + threadIdx.x;
    if (g >= N * 8) return;
    int r = g >> 3, h = g & 7;
    const float* hp = h1 + r * 128 + h * 16;
    const float* sp = as + h * 16;
    const float* dp = ad + h * 16;
    float s = 0.f, d = 0.f;
#pragma unroll
    for (int q = 0; q < 16; ++q) {
        float v = hp[q];
        s = fmaf(v, sp[q], s);
        d = fmaf(v, dp[q], d);
    }
    alS[g] = s;
    alD[g] = d;
}

__global__ __launch_bounds__(256) void al2_kernel(const float* __restrict__ h3,
                                                  const float* __restrict__ as,
                                                  const float* __restrict__ ad,
                                                  float* __restrict__ alS,
                                                  float* __restrict__ alD, int N, int NC) {
    int lane = threadIdx.x & 63;
    int r = blockIdx.x * 4 + (threadIdx.x >> 6);
    if (r >= N) return;
    float s = 0.f, d = 0.f;
    for (int c = lane; c < NC; c += 64) {
        float v = h3[r * NC + c];
        s = fmaf(v, as[c], s);
        d = fmaf(v, ad[c], d);
    }
#pragma unroll
    for (int off = 32; off; off >>= 1) {
        s += __shfl_down(s, off);
        d += __shfl_down(d, off);
    }
    if (lane == 0) { alS[r] = s; alD[r] = d; }
}

// ---------------- layer-1 aggregation: single pass, global-max stabilized ----------------

__global__ __launch_bounds__(128) void agg1_kernel(
    const float* __restrict__ h1, const float* __restrict__ alS,
    const float* __restrict__ alD, const float* __restrict__ b1,
    const int* __restrict__ rp, const int* __restrict__ csr,
    const unsigned* __restrict__ gm, float* __restrict__ h2, int N) {
    int t = blockIdx.x;
    int tid = threadIdx.x;
    int h = tid >> 4;
    float adT = alD[t * 8 + h];
    float m = lrelu(funkey(gm[h]) + adT);
    int e0 = rp[t], e1 = rp[t + 1];

    float ex = __expf(lrelu(alS[t * 8 + h] + adT) - m);
    float dsum = ex;
    float facc = ex * h1[t * 128 + tid];

    int e = e0;
    for (; e + 2 <= e1; e += 2) {
        int s0 = csr[e], s1 = csr[e + 1];
        float w0 = __expf(lrelu(alS[s0 * 8 + h] + adT) - m);
        float w1 = __expf(lrelu(alS[s1 * 8 + h] + adT) - m);
        float f0 = h1[s0 * 128 + tid];
        float f1 = h1[s1 * 128 + tid];
        dsum += w0 + w1;
        facc = fmaf(w0, f0, facc);
        facc = fmaf(w1, f1, facc);
    }
    if (e < e1) {
        int s0 = csr[e];
        float w0 = __expf(lrelu(alS[s0 * 8 + h] + adT) - m);
        dsum += w0;
        facc = fmaf(w0, h1[s0 * 128 + tid], facc);
    }
    float o = facc / dsum + b1[tid];
    h2[t * 128 + tid] = fmaxf(o, 0.0f);
}

// ---------------- layer-2 aggregation: single pass ----------------

__global__ __launch_bounds__(128) void agg2_kernel(
    const float* __restrict__ h3, const float* __restrict__ alS,
    const float* __restrict__ alD, const float* __restrict__ b2,
    const int* __restrict__ rp, const int* __restrict__ csr,
    const unsigned* __restrict__ gm, float* __restrict__ out, int N, int NC) {
    int t = blockIdx.x;
    int tid = threadIdx.x;
    float adT = alD[t];
    float m = lrelu(funkey(gm[0]) + adT);
    int e0 = rp[t], e1 = rp[t + 1];

    float ex = __expf(lrelu(alS[t] + adT) - m);
    float dsum = ex;
    float facc = (tid < NC) ? ex * h3[t * NC + tid] : 0.0f;

    int e = e0;
    for (; e + 2 <= e1; e += 2) {
        int s0 = csr[e], s1 = csr[e + 1];
        float w0 = __expf(lrelu(alS[s0] + adT) - m);
        float w1 = __expf(lrelu(alS[s1] + adT) - m);
        float f0 = (tid < NC) ? h3[s0 * NC + tid] : 0.0f;
        float f1 = (tid < NC) ? h3[s1 * NC + tid] : 0.0f;
        dsum += w0 + w1;
        facc = fmaf(w0, f0, facc);
        facc = fmaf(w1, f1, facc);
    }
    if (e < e1) {
        int s0 = csr[e];
        float w0 = __expf(lrelu(alS[s0] + adT) - m);
        dsum += w0;
        if (tid < NC) facc = fmaf(w0, h3[s0 * NC + tid], facc);
    }
    if (tid < NC) out[t * NC + tid] = facc / dsum + b2[tid];
}

// ---------------- host launcher ----------------

extern "C" void kernel_launch(void* const* d_in, const int* in_sizes, int n_in,
                              void* d_out, int out_size, void* d_ws, size_t ws_size,
                              hipStream_t stream) {
    const float* x   = (const float*)d_in[0];
    const int*   ei  = (const int*)d_in[1];
    const float* W1  = (const float*)d_in[2];
    const float* aS1 = (const float*)d_in[3];
    const float* aD1 = (const float*)d_in[4];
    const float* b1  = (const float*)d_in[5];
    const float* W2  = (const float*)d_in[6];
    const float* aS2 = (const float*)d_in[7];
    const float* aD2 = (const float*)d_in[8];
    const float* b2  = (const float*)d_in[9];
    float* out = (float*)d_out;

    const int N = in_sizes[0] / 128;   // 50000
    const int E = in_sizes[1] / 2;     // 800000
    const int NC2 = 121;

    size_t off = 0;
    auto alloc = [&](size_t bytes) {
        size_t o = off;
        off = (off + bytes + 255) & ~(size_t)255;
        return o;
    };
    char* ws = (char*)d_ws;
    int*      cnt  = (int*)(ws + alloc((size_t)N * 4));
    int*      fill = (int*)(ws + alloc((size_t)N * 4));
    int*      rp   = (int*)(ws + alloc((size_t)(N + 1) * 4));
    int*      csr  = (int*)(ws + alloc((size_t)E * 4));
    int*      bsum = (int*)(ws + alloc(64 * 4));
    float*    alS1 = (float*)(ws + alloc((size_t)N * 8 * 4));
    float*    alD1 = (float*)(ws + alloc((size_t)N * 8 * 4));
    float*    alS2 = (float*)(ws + alloc((size_t)N * 4));
    float*    alD2 = (float*)(ws + alloc((size_t)N * 4));
    unsigned* gm1  = (unsigned*)(ws + alloc(8 * 4));
    unsigned* gm2  = (unsigned*)(ws + alloc(4));
    float*    h1   = (float*)(ws + alloc((size_t)N * 128 * 4));
    float*    h2   = (float*)(ws + alloc((size_t)N * 128 * 4));
    float*    h3   = h1;  // h1 dead after agg1
    if (ws_size < off) return;

    const int* src = ei;
    const int* dst = ei + E;

    hipMemsetAsync(cnt, 0, (size_t)N * 4, stream);
    hipMemsetAsync(fill, 0, (size_t)N * 4, stream);
    hipMemsetAsync(gm1, 0, 8 * 4, stream);
    hipMemsetAsync(gm2, 0, 4, stream);

    int eb = (E + 255) / 256;
    int nb = (N + 1023) / 1024;  // 49 (must be <= 64)
    hist_kernel<<<eb, 256, 0, stream>>>(dst, cnt, E);
    scan_reduce<<<nb, 256, 0, stream>>>(cnt, bsum, N);
    scan_bsum<<<1, 64, 0, stream>>>(bsum, nb);
    scan_write<<<nb, 256, 0, stream>>>(cnt, bsum, rp, N);
    scatter_kernel<<<eb, 256, 0, stream>>>(src, dst, rp, fill, csr, E);

    int gb = (N + 127) / 128;
    gemm_k128<128><<<gb, 256, 0, stream>>>(x, W1, h1, N);
    al1_kernel<<<(N * 8 + 255) / 256, 256, 0, stream>>>(h1, aS1, aD1, alS1, alD1, N);
    gmax_kernel<8><<<128, 256, 0, stream>>>(alS1, gm1, N * 8);
    agg1_kernel<<<N, 128, 0, stream>>>(h1, alS1, alD1, b1, rp, csr, gm1, h2, N);

    gemm_k128<121><<<gb, 256, 0, stream>>>(h2, W2, h3, N);
    al2_kernel<<<(N + 3) / 4, 256, 0, stream>>>(h3, aS2, aD2, alS2, alD2, N, NC2);
    gmax_kernel<1><<<128, 256, 0, stream>>>(alS2, gm2, N);
    agg2_kernel<<<N, 128, 0, stream>>>(h3, alS2, alD2, b2, rp, csr, gm2, out, N, NC2);
}